// Round 18
// baseline (1952.278 us; speedup 1.0000x reference)
//
#include <hip/hip_runtime.h>

#define NN 50000
#define HID 128
#define IN_C 100
#define OUT_C 40

// ---------------------------------------------------------------------------
__global__ __launch_bounds__(256)
void hist_kernel(const int* __restrict__ dst, int* __restrict__ deg, int E) {
    int e = blockIdx.x * 256 + threadIdx.x;
    if (e < E) atomicAdd(&deg[dst[e]], 1);
}

// ---------------------------------------------------------------------------
__global__ __launch_bounds__(256)
void chunk_sum_kernel(const int* __restrict__ deg, int* __restrict__ chunk_sums, int N) {
    __shared__ int s[256];
    const int t = threadIdx.x;
    const int i = blockIdx.x * 256 + t;
    s[t] = (i < N) ? deg[i] : 0;
    __syncthreads();
    for (int o = 128; o; o >>= 1) { if (t < o) s[t] += s[t + o]; __syncthreads(); }
    if (t == 0) chunk_sums[blockIdx.x] = s[0];
}

__global__ __launch_bounds__(256)
void chunk_scan_kernel(int* __restrict__ chunk_sums, int M) {
    __shared__ int s[256];
    const int t = threadIdx.x;
    int v = (t < M) ? chunk_sums[t] : 0;
    s[t] = v;
    __syncthreads();
    for (int o = 1; o < 256; o <<= 1) {
        int x = (t >= o) ? s[t - o] : 0;
        __syncthreads();
        s[t] += x;
        __syncthreads();
    }
    if (t < M) chunk_sums[t] = s[t] - v;   // exclusive
}

__global__ __launch_bounds__(256)
void chunk_apply_kernel(const int* __restrict__ deg, const int* __restrict__ chunk_sums,
                        int* __restrict__ row_start, int* __restrict__ cursor, int N) {
    __shared__ int s[256];
    const int t = threadIdx.x;
    const int i = blockIdx.x * 256 + t;
    int v = (i < N) ? deg[i] : 0;
    s[t] = v;
    __syncthreads();
    for (int o = 1; o < 256; o <<= 1) {
        int x = (t >= o) ? s[t - o] : 0;
        __syncthreads();
        s[t] += x;
        __syncthreads();
    }
    if (i < N) {
        int ex = chunk_sums[blockIdx.x] + s[t] - v;
        row_start[i] = ex;
        cursor[i] = ex;
        if (i == N - 1) row_start[N] = ex + v;
    }
}

// ---------------------------------------------------------------------------
__global__ __launch_bounds__(256)
void scatter_kernel(const int* __restrict__ src, const int* __restrict__ dst,
                    int* __restrict__ cursor, int* __restrict__ csr_src, int E) {
    int e = blockIdx.x * 256 + threadIdx.x;
    if (e < E) {
        int pos = atomicAdd(&cursor[dst[e]], 1);
        csr_src[pos] = src[e];
    }
}

// ---------------------------------------------------------------------------
__device__ __forceinline__ double2 ld2(const double* p) {
    return *(const double2*)p;
}
__device__ __forceinline__ double2 ld2(const float* p) {
    float2 v = *(const float2*)p;
    return make_double2((double)v.x, (double)v.y);
}

// ---------------------------------------------------------------------------
// r15 golden structure, 16 nodes/block (4 nodes/thread in GEMM) to amortize
// the weight stream: per 8 f64 FMA the thread issues {2 w-loads + 2 cvt +
// 8 ds_read} vs r15's {4 loads + 4 cvt + 8 ds_read} -- 17% fewer issue slots
// per FMA, and halves per-layer L2 weight traffic. LDS 57.9KB -> 2 blocks/CU.
// Per-node arithmetic (gather order, GEMM k-order, RVQ recipe) is verbatim
// r15 -- numerics unchanged.
// Numerics recipe (DO NOT CHANGE): f64 h end-to-end; all accumulation f64;
// d2 = fl32(fl32(rr32 - 2*rc32) + cc32); argmin = first-min.
template<int K, bool HAS_BN, bool LAST, typename TIN>
__global__ __launch_bounds__(512, 4)
void layer_fused(const TIN* __restrict__ h_in,
                 const int* __restrict__ row_start, const int* __restrict__ csr_src,
                 const float* __restrict__ Wa, const float* __restrict__ Wr,
                 const float* __restrict__ b,
                 const float* __restrict__ gamma, const float* __restrict__ beta,
                 const float* __restrict__ mean, const float* __restrict__ var,
                 const float* __restrict__ cb,       // [3*16*128] this layer
                 double* __restrict__ h_out,
                 float* __restrict__ ids_out, int id_col0,
                 double* __restrict__ loss_part,
                 const float* __restrict__ lin_W, const float* __restrict__ lin_b,
                 float* __restrict__ out) {
    __shared__ double s_agg[16][HID];  // phase A: agg; phase C/D: h rows (rvq res)
    __shared__ double s_h[16][HID];    // root rows; LAST: output rows for head
    __shared__ float s_cb[3 * 16 * 129];   // padded stride 129
    __shared__ float s_cc32[3][16];
    __shared__ double s_ws[8];
    const int t = threadIdx.x;
    const int w = t >> 6, lane = t & 63;
    const int n0 = blockIdx.x * 16;

    // ---- codebook -> LDS (padded) ----
    for (int idx = t; idx < 3 * 16 * 128; idx += 512)
        s_cb[(idx >> 7) * 129 + (idx & 127)] = cb[idx];

    // ---- phase A: wave w gathers nodes n0+w and n0+w+8 (r15 arithmetic) ----
    for (int it = 0; it < 2; ++it) {
        const int p = w + it * 8;
        const int n = n0 + p;
        const int r0 = row_start[n], r1 = row_start[n + 1];
        const int f0 = 2 * lane;
        if (f0 < K) {
            double s0 = 0, s1 = 0, s2 = 0, s3 = 0, s4 = 0, s5 = 0, s6 = 0, s7 = 0;
            int i = r0;
            for (; i + 3 < r1; i += 4) {
                const double2 v0 = ld2(h_in + (size_t)csr_src[i] * K + f0);
                const double2 v1 = ld2(h_in + (size_t)csr_src[i + 1] * K + f0);
                const double2 v2 = ld2(h_in + (size_t)csr_src[i + 2] * K + f0);
                const double2 v3 = ld2(h_in + (size_t)csr_src[i + 3] * K + f0);
                s0 += v0.x; s1 += v0.y; s2 += v1.x; s3 += v1.y;
                s4 += v2.x; s5 += v2.y; s6 += v3.x; s7 += v3.y;
            }
            for (; i < r1; ++i) {
                const double2 v = ld2(h_in + (size_t)csr_src[i] * K + f0);
                s0 += v.x; s1 += v.y;
            }
            const int deg = r1 - r0;
            const double dd = (double)(deg > 1 ? deg : 1);
            const double2 root = ld2(h_in + (size_t)n * K + f0);
            s_agg[p][f0]     = ((s0 + s2) + (s4 + s6)) / dd;
            s_agg[p][f0 + 1] = ((s1 + s3) + (s5 + s7)) / dd;
            s_h[p][f0]     = root.x;
            s_h[p][f0 + 1] = root.y;
        }
    }
    __syncthreads();

    // ---- phase B: GEMM, 4 nodes/thread, direct f32 weight loads ----
    const int col = t & 127;
    const int p4 = t >> 7;      // 0..3; nodes p4, p4+4, p4+8, p4+12
    double acc0 = (double)b[col];
    double acc1 = acc0, acc2 = acc0, acc3 = acc0;
#pragma unroll 4
    for (int k = 0; k < K; ++k) {
        const double wa = (double)Wa[(size_t)k * HID + col];
        const double wr = (double)Wr[(size_t)k * HID + col];
        acc0 += s_agg[p4][k] * wa + s_h[p4][k] * wr;
        acc1 += s_agg[p4 + 4][k] * wa + s_h[p4 + 4][k] * wr;
        acc2 += s_agg[p4 + 8][k] * wa + s_h[p4 + 8][k] * wr;
        acc3 += s_agg[p4 + 12][k] * wa + s_h[p4 + 12][k] * wr;
    }
    __syncthreads();   // all GEMM reads of s_agg/s_h complete

    // ---- phase C: BN(f64)+ReLU, write f64 h, stash rows for RVQ (and head) ----
    {
        double scale = 1.0, shift = 0.0;
        if (HAS_BN) {
            scale = (double)gamma[col] / sqrt((double)var[col] + 1e-5);
            shift = (double)beta[col] - (double)mean[col] * scale;
        }
        double accs[4] = {acc0, acc1, acc2, acc3};
#pragma unroll
        for (int q4 = 0; q4 < 4; ++q4) {
            const int p = p4 + q4 * 4;
            double v = accs[q4];
            if (HAS_BN) {
                v = v * scale + shift;
                v = v > 0.0 ? v : 0.0;
            }
            h_out[(size_t)(n0 + p) * HID + col] = v;
            s_agg[p][col] = v;
            if (LAST) s_h[p][col] = v;
        }
    }
    if (t < 48) {
        const float* c = &s_cb[t * 129];
        double s = 0.0;
        for (int j = 0; j < 128; j++) { double cj = (double)c[j]; s += cj * cj; }
        s_cc32[t >> 4][t & 15] = (float)s;
    }
    __syncthreads();

    // ---- phase D: RVQ, wave w on nodes w and w+8 (wave-lockstep) ----
    {
        const int k = lane & 15, q = lane >> 4;
        double wlsum = 0.0;

        for (int it = 0; it < 2; ++it) {
            const int p = w + it * 8;
            double* res = &s_agg[p][0];
            const int n = n0 + p;

            for (int g = 0; g < 3; ++g) {
                // rr = ||res||^2 (f64 butterfly)
                double r0 = res[lane], r1 = res[lane + 64];
                double pr = r0 * r0 + r1 * r1;
                pr += __shfl_xor(pr, 1, 64);
                pr += __shfl_xor(pr, 2, 64);
                pr += __shfl_xor(pr, 4, 64);
                pr += __shfl_xor(pr, 8, 64);
                pr += __shfl_xor(pr, 16, 64);
                pr += __shfl_xor(pr, 32, 64);
                const float rr32 = (float)pr;

                // dot(res, c_k): lane (k,q) does quarter q with q-rotation
                const float* c = &s_cb[(g * 16 + k) * 129];
                double dot = 0.0;
#pragma unroll
                for (int j2 = 0; j2 < 32; ++j2) {
                    int j = q * 32 + ((j2 + q * 8) & 31);
                    dot += res[j] * (double)c[j];
                }
                dot += __shfl_xor(dot, 16, 64);
                dot += __shfl_xor(dot, 32, 64);

                const float rc32 = (float)dot;
                const float t1 = rr32 - 2.0f * rc32;     // fp32 round
                const float d2 = t1 + s_cc32[g][k];      // fp32 round

                // first-min argmin over 16 codes (butterfly, tie -> smaller idx)
                float bv = d2; int bk = k;
                {
                    float ov; int ok;
                    ov = __shfl_xor(bv, 1, 64); ok = __shfl_xor(bk, 1, 64);
                    if (ov < bv || (ov == bv && ok < bk)) { bv = ov; bk = ok; }
                    ov = __shfl_xor(bv, 2, 64); ok = __shfl_xor(bk, 2, 64);
                    if (ov < bv || (ov == bv && ok < bk)) { bv = ov; bk = ok; }
                    ov = __shfl_xor(bv, 4, 64); ok = __shfl_xor(bk, 4, 64);
                    if (ov < bv || (ov == bv && ok < bk)) { bv = ov; bk = ok; }
                    ov = __shfl_xor(bv, 8, 64); ok = __shfl_xor(bk, 8, 64);
                    if (ov < bv || (ov == bv && ok < bk)) { bv = ov; bk = ok; }
                }
                if (lane == 0)
                    ids_out[(size_t)n * 9 + id_col0 + g] = (float)bk;

                res[lane]      -= (double)s_cb[(g * 16 + bk) * 129 + lane];
                res[lane + 64] -= (double)s_cb[(g * 16 + bk) * 129 + lane + 64];
            }
            double r0 = res[lane], r1 = res[lane + 64];
            double wl = r0 * r0 + r1 * r1;
            wl += __shfl_xor(wl, 1, 64);
            wl += __shfl_xor(wl, 2, 64);
            wl += __shfl_xor(wl, 4, 64);
            wl += __shfl_xor(wl, 8, 64);
            wl += __shfl_xor(wl, 16, 64);
            wl += __shfl_xor(wl, 32, 64);
            wlsum += wl;
        }
        if (lane == 0) s_ws[w] = wlsum;
    }

    // ---- phase E (LAST only): linear head, wave w on nodes w and w+8 ----
    if (LAST) {
        for (int it = 0; it < 2; ++it) {
            const int p = w + it * 8;
            const int n = n0 + p;
            if (lane < OUT_C) {
                double acc = (double)lin_b[lane];
                for (int kk = 0; kk < HID; ++kk)
                    acc += s_h[p][kk] * (double)lin_W[kk * OUT_C + lane];
                out[(size_t)n * OUT_C + lane] = (float)acc;
            }
        }
    }

    __syncthreads();
    if (t == 0) {
        double s = 0.0;
#pragma unroll
        for (int i = 0; i < 8; i++) s += s_ws[i];
        loss_part[blockIdx.x] = s;
    }
}

// ---------------------------------------------------------------------------
__global__ __launch_bounds__(256)
void finalize_kernel(const double* __restrict__ loss_part, int M,
                     float* __restrict__ out_loss) {
    __shared__ double s[256];
    const int t = threadIdx.x;
    double v = 0.0;
    for (int i = t; i < M; i += 256) v += loss_part[i];
    s[t] = v;
    __syncthreads();
    for (int off = 128; off; off >>= 1) {
        if (t < off) s[t] += s[t + off];
        __syncthreads();
    }
    if (t == 0) out_loss[0] = (float)(s[0] / ((double)NN * (double)HID));
}

// ---------------------------------------------------------------------------
extern "C" void kernel_launch(void* const* d_in, const int* in_sizes, int n_in,
                              void* d_out, int out_size, void* d_ws, size_t ws_size,
                              hipStream_t stream) {
    const float* x    = (const float*)d_in[0];
    const int*   src  = (const int*)d_in[1];
    const int*   dst  = (const int*)d_in[2];
    const float* W0a = (const float*)d_in[3];
    const float* W0r = (const float*)d_in[4];
    const float* b0  = (const float*)d_in[5];
    const float* W1a = (const float*)d_in[6];
    const float* W1r = (const float*)d_in[7];
    const float* b1  = (const float*)d_in[8];
    const float* W2a = (const float*)d_in[9];
    const float* W2r = (const float*)d_in[10];
    const float* b2  = (const float*)d_in[11];
    const float* bn_gamma = (const float*)d_in[12];
    const float* bn_beta  = (const float*)d_in[13];
    const float* bn_mean  = (const float*)d_in[14];
    const float* bn_var   = (const float*)d_in[15];
    const float* cb    = (const float*)d_in[16];
    const float* lin_W = (const float*)d_in[17];
    const float* lin_b = (const float*)d_in[18];

    const int E = in_sizes[1];

    float* out      = (float*)d_out;                    // [N*40]
    float* out_loss = out + (size_t)NN * OUT_C;         // [1]
    float* out_ids  = out_loss + 1;                     // [N*9] as float

    // ---- workspace layout, 512B-aligned segments ----
    char* base = (char*)d_ws;
    size_t off = 0;
    auto alloc = [&](size_t bytes) -> void* {
        off = (off + 511) & ~(size_t)511;
        void* p = base + off;
        off += bytes;
        return p;
    };
    int* deg_i      = (int*)alloc((size_t)NN * 4);
    int* row_start  = (int*)alloc((size_t)(NN + 1) * 4);
    int* cursor     = (int*)alloc((size_t)NN * 4);
    int* csr_src    = (int*)alloc((size_t)E * 4);
    int* chunk_sums = (int*)alloc(256 * 4);
    double* loss_part = (double*)alloc((size_t)3 * 3125 * 8);
    double* h1 = (double*)alloc((size_t)NN * HID * 8);  // f64 h
    double* h2 = (double*)alloc((size_t)NN * HID * 8);

    const int cb_layer = 3 * 16 * HID;
    const int NB = NN / 16;                             // 3125 blocks
    const int NCHUNK = (NN + 255) / 256;                // 196

    // ---- CSR build ----
    hipMemsetAsync(deg_i, 0, NN * sizeof(int), stream);
    hist_kernel<<<(E + 255) / 256, 256, 0, stream>>>(dst, deg_i, E);
    chunk_sum_kernel<<<NCHUNK, 256, 0, stream>>>(deg_i, chunk_sums, NN);
    chunk_scan_kernel<<<1, 256, 0, stream>>>(chunk_sums, NCHUNK);
    chunk_apply_kernel<<<NCHUNK, 256, 0, stream>>>(deg_i, chunk_sums, row_start, cursor, NN);
    scatter_kernel<<<(E + 255) / 256, 256, 0, stream>>>(src, dst, cursor, csr_src, E);

    // ---- fused layers ----
    layer_fused<IN_C, true, false, float><<<NB, 512, 0, stream>>>(
        x, row_start, csr_src, W0a, W0r, b0, bn_gamma, bn_beta, bn_mean, bn_var,
        cb + 0 * cb_layer, h1, out_ids, 0, loss_part, nullptr, nullptr, nullptr);

    layer_fused<HID, true, false, double><<<NB, 512, 0, stream>>>(
        h1, row_start, csr_src, W1a, W1r, b1,
        bn_gamma + HID, bn_beta + HID, bn_mean + HID, bn_var + HID,
        cb + 1 * cb_layer, h2, out_ids, 3, loss_part + NB, nullptr, nullptr, nullptr);

    layer_fused<HID, false, true, double><<<NB, 512, 0, stream>>>(
        h2, row_start, csr_src, W2a, W2r, b2, nullptr, nullptr, nullptr, nullptr,
        cb + 2 * cb_layer, h1, out_ids, 6, loss_part + 2 * NB, lin_W, lin_b, out);

    // ---- loss ----
    finalize_kernel<<<1, 256, 0, stream>>>(loss_part, 3 * NB, out_loss);
}

// Round 19
// 947.250 us; speedup vs baseline: 2.0610x; 2.0610x over previous
//
#include <hip/hip_runtime.h>

#define NN 50000
#define HID 128
#define IN_C 100
#define OUT_C 40

// ---------------------------------------------------------------------------
__global__ __launch_bounds__(256)
void hist_kernel(const int* __restrict__ dst, int* __restrict__ deg, int E) {
    int e = blockIdx.x * 256 + threadIdx.x;
    if (e < E) atomicAdd(&deg[dst[e]], 1);
}

// ---------------------------------------------------------------------------
__global__ __launch_bounds__(256)
void chunk_sum_kernel(const int* __restrict__ deg, int* __restrict__ chunk_sums, int N) {
    __shared__ int s[256];
    const int t = threadIdx.x;
    const int i = blockIdx.x * 256 + t;
    s[t] = (i < N) ? deg[i] : 0;
    __syncthreads();
    for (int o = 128; o; o >>= 1) { if (t < o) s[t] += s[t + o]; __syncthreads(); }
    if (t == 0) chunk_sums[blockIdx.x] = s[0];
}

__global__ __launch_bounds__(256)
void chunk_scan_kernel(int* __restrict__ chunk_sums, int M) {
    __shared__ int s[256];
    const int t = threadIdx.x;
    int v = (t < M) ? chunk_sums[t] : 0;
    s[t] = v;
    __syncthreads();
    for (int o = 1; o < 256; o <<= 1) {
        int x = (t >= o) ? s[t - o] : 0;
        __syncthreads();
        s[t] += x;
        __syncthreads();
    }
    if (t < M) chunk_sums[t] = s[t] - v;   // exclusive
}

__global__ __launch_bounds__(256)
void chunk_apply_kernel(const int* __restrict__ deg, const int* __restrict__ chunk_sums,
                        int* __restrict__ row_start, int* __restrict__ cursor, int N) {
    __shared__ int s[256];
    const int t = threadIdx.x;
    const int i = blockIdx.x * 256 + t;
    int v = (i < N) ? deg[i] : 0;
    s[t] = v;
    __syncthreads();
    for (int o = 1; o < 256; o <<= 1) {
        int x = (t >= o) ? s[t - o] : 0;
        __syncthreads();
        s[t] += x;
        __syncthreads();
    }
    if (i < N) {
        int ex = chunk_sums[blockIdx.x] + s[t] - v;
        row_start[i] = ex;
        cursor[i] = ex;
        if (i == N - 1) row_start[N] = ex + v;
    }
}

// ---------------------------------------------------------------------------
__global__ __launch_bounds__(256)
void scatter_kernel(const int* __restrict__ src, const int* __restrict__ dst,
                    int* __restrict__ cursor, int* __restrict__ csr_src, int E) {
    int e = blockIdx.x * 256 + threadIdx.x;
    if (e < E) {
        int pos = atomicAdd(&cursor[dst[e]], 1);
        csr_src[pos] = src[e];
    }
}

// ---------------------------------------------------------------------------
__device__ __forceinline__ double2 ld2(const double* p) {
    return *(const double2*)p;
}
__device__ __forceinline__ double2 ld2(const float* p) {
    float2 v = *(const float2*)p;
    return make_double2((double)v.x, (double)v.y);
}

// ---------------------------------------------------------------------------
// GOLDEN layer kernel (r15 = best, 953us total). fused: mean-aggregate (CSR
// gather, f64, 4-deep unroll) + GEMM (direct f32 weight loads, f64 accumulate)
// + BN(f64)/ReLU + RVQ [+ LAST: linear head fused].
// 512 threads = 8 waves, 8 nodes/block, wave-per-node gather & rvq.
// Numerics recipe (DO NOT CHANGE): f64 h end-to-end; all accumulation f64;
// d2 = fl32(fl32(rr32 - 2*rc32) + cc32); argmin = first-min.
template<int K, bool HAS_BN, bool LAST, typename TIN>
__global__ __launch_bounds__(512, 6)
void layer_fused(const TIN* __restrict__ h_in,
                 const int* __restrict__ row_start, const int* __restrict__ csr_src,
                 const float* __restrict__ Wa, const float* __restrict__ Wr,
                 const float* __restrict__ b,
                 const float* __restrict__ gamma, const float* __restrict__ beta,
                 const float* __restrict__ mean, const float* __restrict__ var,
                 const float* __restrict__ cb,       // [3*16*128] this layer
                 double* __restrict__ h_out,
                 float* __restrict__ ids_out, int id_col0,
                 double* __restrict__ loss_part,
                 const float* __restrict__ lin_W, const float* __restrict__ lin_b,
                 float* __restrict__ out) {
    __shared__ double s_agg[8][HID];   // phase A: agg; phase C/D: h rows (rvq res)
    __shared__ double s_h[8][HID];     // root rows; LAST: output rows for head
    __shared__ float s_cb[3 * 16 * 129];   // padded stride 129
    __shared__ float s_cc32[3][16];
    __shared__ double s_ws[8];
    const int t = threadIdx.x;
    const int w = t >> 6, lane = t & 63;
    const int n0 = blockIdx.x * 8;

    // ---- codebook -> LDS (padded) ----
    for (int idx = t; idx < 3 * 16 * 128; idx += 512)
        s_cb[(idx >> 7) * 129 + (idx & 127)] = cb[idx];

    // ---- phase A: wave w gathers node n0+w; lane covers features 2l, 2l+1 ----
    {
        const int n = n0 + w;
        const int r0 = row_start[n], r1 = row_start[n + 1];
        const int f0 = 2 * lane;
        if (f0 < K) {
            double s0 = 0, s1 = 0, s2 = 0, s3 = 0, s4 = 0, s5 = 0, s6 = 0, s7 = 0;
            int i = r0;
            for (; i + 3 < r1; i += 4) {
                const double2 v0 = ld2(h_in + (size_t)csr_src[i] * K + f0);
                const double2 v1 = ld2(h_in + (size_t)csr_src[i + 1] * K + f0);
                const double2 v2 = ld2(h_in + (size_t)csr_src[i + 2] * K + f0);
                const double2 v3 = ld2(h_in + (size_t)csr_src[i + 3] * K + f0);
                s0 += v0.x; s1 += v0.y; s2 += v1.x; s3 += v1.y;
                s4 += v2.x; s5 += v2.y; s6 += v3.x; s7 += v3.y;
            }
            for (; i < r1; ++i) {
                const double2 v = ld2(h_in + (size_t)csr_src[i] * K + f0);
                s0 += v.x; s1 += v.y;
            }
            const int deg = r1 - r0;
            const double dd = (double)(deg > 1 ? deg : 1);
            const double2 root = ld2(h_in + (size_t)n * K + f0);
            s_agg[w][f0]     = ((s0 + s2) + (s4 + s6)) / dd;
            s_agg[w][f0 + 1] = ((s1 + s3) + (s5 + s7)) / dd;
            s_h[w][f0]     = root.x;
            s_h[w][f0 + 1] = root.y;
        }
    }
    __syncthreads();

    // ---- phase B: GEMM, direct f32 weight loads, f64 accumulate ----
    const int col = t & 127;
    const int p4 = t >> 7;      // 0..3; nodes p4 and p4+4
    double accA = (double)b[col];
    double accB = accA;
#pragma unroll 4
    for (int k = 0; k < K; ++k) {
        const double wa = (double)Wa[(size_t)k * HID + col];
        const double wr = (double)Wr[(size_t)k * HID + col];
        accA += s_agg[p4][k] * wa + s_h[p4][k] * wr;
        accB += s_agg[p4 + 4][k] * wa + s_h[p4 + 4][k] * wr;
    }
    __syncthreads();   // all GEMM reads of s_agg/s_h complete

    // ---- phase C: BN(f64)+ReLU, write f64 h, stash rows for RVQ (and head) ----
    {
        double vA = accA, vB = accB;
        if (HAS_BN) {
            const double scale = (double)gamma[col] / sqrt((double)var[col] + 1e-5);
            const double shift = (double)beta[col] - (double)mean[col] * scale;
            vA = vA * scale + shift; vA = vA > 0.0 ? vA : 0.0;
            vB = vB * scale + shift; vB = vB > 0.0 ? vB : 0.0;
        }
        h_out[(size_t)(n0 + p4) * HID + col] = vA;
        h_out[(size_t)(n0 + p4 + 4) * HID + col] = vB;
        s_agg[p4][col] = vA;
        s_agg[p4 + 4][col] = vB;
        if (LAST) {                      // keep output rows for the linear head
            s_h[p4][col] = vA;
            s_h[p4 + 4][col] = vB;
        }
    }
    if (t < 48) {
        const float* c = &s_cb[t * 129];
        double s = 0.0;
        for (int j = 0; j < 128; j++) { double cj = (double)c[j]; s += cj * cj; }
        s_cc32[t >> 4][t & 15] = (float)s;
    }
    __syncthreads();

    // ---- phase D: RVQ, wave w on its node (wave-lockstep, no barriers) ----
    {
        double* res = &s_agg[w][0];
        const int n = n0 + w;
        const int k = lane & 15, q = lane >> 4;

        for (int g = 0; g < 3; ++g) {
            // rr = ||res||^2 (f64 butterfly)
            double r0 = res[lane], r1 = res[lane + 64];
            double pr = r0 * r0 + r1 * r1;
            pr += __shfl_xor(pr, 1, 64);
            pr += __shfl_xor(pr, 2, 64);
            pr += __shfl_xor(pr, 4, 64);
            pr += __shfl_xor(pr, 8, 64);
            pr += __shfl_xor(pr, 16, 64);
            pr += __shfl_xor(pr, 32, 64);
            const float rr32 = (float)pr;

            // dot(res, c_k): lane (k,q) does quarter q with q-rotation
            const float* c = &s_cb[(g * 16 + k) * 129];
            double dot = 0.0;
#pragma unroll
            for (int j2 = 0; j2 < 32; ++j2) {
                int j = q * 32 + ((j2 + q * 8) & 31);
                dot += res[j] * (double)c[j];
            }
            dot += __shfl_xor(dot, 16, 64);
            dot += __shfl_xor(dot, 32, 64);

            const float rc32 = (float)dot;
            const float t1 = rr32 - 2.0f * rc32;     // fp32 round
            const float d2 = t1 + s_cc32[g][k];      // fp32 round

            // first-min argmin over 16 codes (butterfly, tie -> smaller idx)
            float bv = d2; int bk = k;
            {
                float ov; int ok;
                ov = __shfl_xor(bv, 1, 64); ok = __shfl_xor(bk, 1, 64);
                if (ov < bv || (ov == bv && ok < bk)) { bv = ov; bk = ok; }
                ov = __shfl_xor(bv, 2, 64); ok = __shfl_xor(bk, 2, 64);
                if (ov < bv || (ov == bv && ok < bk)) { bv = ov; bk = ok; }
                ov = __shfl_xor(bv, 4, 64); ok = __shfl_xor(bk, 4, 64);
                if (ov < bv || (ov == bv && ok < bk)) { bv = ov; bk = ok; }
                ov = __shfl_xor(bv, 8, 64); ok = __shfl_xor(bk, 8, 64);
                if (ov < bv || (ov == bv && ok < bk)) { bv = ov; bk = ok; }
            }
            if (lane == 0)
                ids_out[(size_t)n * 9 + id_col0 + g] = (float)bk;

            res[lane]      -= (double)s_cb[(g * 16 + bk) * 129 + lane];
            res[lane + 64] -= (double)s_cb[(g * 16 + bk) * 129 + lane + 64];
        }
        double r0 = res[lane], r1 = res[lane + 64];
        double wl = r0 * r0 + r1 * r1;
        wl += __shfl_xor(wl, 1, 64);
        wl += __shfl_xor(wl, 2, 64);
        wl += __shfl_xor(wl, 4, 64);
        wl += __shfl_xor(wl, 8, 64);
        wl += __shfl_xor(wl, 16, 64);
        wl += __shfl_xor(wl, 32, 64);
        if (lane == 0) s_ws[w] = wl;
    }

    // ---- phase E (LAST only): linear head, wave w on its node ----
    if (LAST) {
        const int n = n0 + w;
        if (lane < OUT_C) {
            double acc = (double)lin_b[lane];
            for (int kk = 0; kk < HID; ++kk)
                acc += s_h[w][kk] * (double)lin_W[kk * OUT_C + lane];
            out[(size_t)n * OUT_C + lane] = (float)acc;
        }
    }

    __syncthreads();
    if (t == 0) {
        double s = 0.0;
#pragma unroll
        for (int i = 0; i < 8; i++) s += s_ws[i];
        loss_part[blockIdx.x] = s;
    }
}

// ---------------------------------------------------------------------------
__global__ __launch_bounds__(256)
void finalize_kernel(const double* __restrict__ loss_part, int M,
                     float* __restrict__ out_loss) {
    __shared__ double s[256];
    const int t = threadIdx.x;
    double v = 0.0;
    for (int i = t; i < M; i += 256) v += loss_part[i];
    s[t] = v;
    __syncthreads();
    for (int off = 128; off; off >>= 1) {
        if (t < off) s[t] += s[t + off];
        __syncthreads();
    }
    if (t == 0) out_loss[0] = (float)(s[0] / ((double)NN * (double)HID));
}

// ---------------------------------------------------------------------------
extern "C" void kernel_launch(void* const* d_in, const int* in_sizes, int n_in,
                              void* d_out, int out_size, void* d_ws, size_t ws_size,
                              hipStream_t stream) {
    const float* x    = (const float*)d_in[0];
    const int*   src  = (const int*)d_in[1];
    const int*   dst  = (const int*)d_in[2];
    const float* W0a = (const float*)d_in[3];
    const float* W0r = (const float*)d_in[4];
    const float* b0  = (const float*)d_in[5];
    const float* W1a = (const float*)d_in[6];
    const float* W1r = (const float*)d_in[7];
    const float* b1  = (const float*)d_in[8];
    const float* W2a = (const float*)d_in[9];
    const float* W2r = (const float*)d_in[10];
    const float* b2  = (const float*)d_in[11];
    const float* bn_gamma = (const float*)d_in[12];
    const float* bn_beta  = (const float*)d_in[13];
    const float* bn_mean  = (const float*)d_in[14];
    const float* bn_var   = (const float*)d_in[15];
    const float* cb    = (const float*)d_in[16];
    const float* lin_W = (const float*)d_in[17];
    const float* lin_b = (const float*)d_in[18];

    const int E = in_sizes[1];

    float* out      = (float*)d_out;                    // [N*40]
    float* out_loss = out + (size_t)NN * OUT_C;         // [1]
    float* out_ids  = out_loss + 1;                     // [N*9] as float

    // ---- workspace layout, 512B-aligned segments ----
    char* base = (char*)d_ws;
    size_t off = 0;
    auto alloc = [&](size_t bytes) -> void* {
        off = (off + 511) & ~(size_t)511;
        void* p = base + off;
        off += bytes;
        return p;
    };
    int* deg_i      = (int*)alloc((size_t)NN * 4);
    int* row_start  = (int*)alloc((size_t)(NN + 1) * 4);
    int* cursor     = (int*)alloc((size_t)NN * 4);
    int* csr_src    = (int*)alloc((size_t)E * 4);
    int* chunk_sums = (int*)alloc(256 * 4);
    double* loss_part = (double*)alloc((size_t)3 * 6250 * 8);
    double* h1 = (double*)alloc((size_t)NN * HID * 8);  // f64 h
    double* h2 = (double*)alloc((size_t)NN * HID * 8);

    const int cb_layer = 3 * 16 * HID;
    const int NB = NN / 8;                              // 6250 blocks
    const int NCHUNK = (NN + 255) / 256;                // 196

    // ---- CSR build ----
    hipMemsetAsync(deg_i, 0, NN * sizeof(int), stream);
    hist_kernel<<<(E + 255) / 256, 256, 0, stream>>>(dst, deg_i, E);
    chunk_sum_kernel<<<NCHUNK, 256, 0, stream>>>(deg_i, chunk_sums, NN);
    chunk_scan_kernel<<<1, 256, 0, stream>>>(chunk_sums, NCHUNK);
    chunk_apply_kernel<<<NCHUNK, 256, 0, stream>>>(deg_i, chunk_sums, row_start, cursor, NN);
    scatter_kernel<<<(E + 255) / 256, 256, 0, stream>>>(src, dst, cursor, csr_src, E);

    // ---- fused layers ----
    layer_fused<IN_C, true, false, float><<<NB, 512, 0, stream>>>(
        x, row_start, csr_src, W0a, W0r, b0, bn_gamma, bn_beta, bn_mean, bn_var,
        cb + 0 * cb_layer, h1, out_ids, 0, loss_part, nullptr, nullptr, nullptr);

    layer_fused<HID, true, false, double><<<NB, 512, 0, stream>>>(
        h1, row_start, csr_src, W1a, W1r, b1,
        bn_gamma + HID, bn_beta + HID, bn_mean + HID, bn_var + HID,
        cb + 1 * cb_layer, h2, out_ids, 3, loss_part + NB, nullptr, nullptr, nullptr);

    layer_fused<HID, false, true, double><<<NB, 512, 0, stream>>>(
        h2, row_start, csr_src, W2a, W2r, b2, nullptr, nullptr, nullptr, nullptr,
        cb + 2 * cb_layer, h1, out_ids, 6, loss_part + 2 * NB, lin_W, lin_b, out);

    // ---- loss ----
    finalize_kernel<<<1, 256, 0, stream>>>(loss_part, 3 * NB, out_loss);
}